// Round 9
// baseline (1578.816 us; speedup 1.0000x reference)
//
#include <hip/hip_runtime.h>
#include <cstdint>

typedef __bf16 bf16x8 __attribute__((ext_vector_type(8)));
typedef __bf16 bf16x4 __attribute__((ext_vector_type(4)));
typedef float  f32x4  __attribute__((ext_vector_type(4)));

#define VOCAB 32000
#define EMB   512
#define HID   1024
#define LAT   512
#define BATCH 32
#define TSTEP 127          // T-1
#define MROWS 4064         // TSTEP*BATCH
#define MPAD  4096
#define G4    4096         // 4*HID
#define NBLK  128          // lstm worker blocks
#define NG    768          // persistent gemm blocks in mega kernel
#define NTM   32           // logits M tiles
#define NTN   250          // logits N tiles

__device__ __forceinline__ float sigf(float x){ return 1.0f / (1.0f + __expf(-x)); }
__device__ __forceinline__ float tanhfast(float x){
    float ax = fabsf(x);
    float e  = __expf(-2.0f * ax);
    float t  = (1.0f - e) / (1.0f + e);
    return copysignf(t, x);
}

// async global->LDS, 16B/lane; LDS base wave-uniform (HW adds lane*16)
__device__ __forceinline__ void gll16(void* lds, const void* gsrc){
    __builtin_amdgcn_global_load_lds(
        (const __attribute__((address_space(1))) unsigned int*)gsrc,
        (__attribute__((address_space(3))) unsigned int*)lds,
        16, 0, 0);
}

// ---------------------------------------------------------------------------
// K0 (grid 192): blocks 0..127: h0 = latent@W_lh^T + b_lh; zero Hall pads;
// zero flags/done. blocks 128..191: W_hh fp32->bf16 (boundary-flushed).
// ---------------------------------------------------------------------------
__global__ __launch_bounds__(256) void init_kernel(
    const float* __restrict__ latent,
    const float* __restrict__ Wlh,
    const float* __restrict__ blh,
    __bf16* __restrict__ h0,
    __bf16* __restrict__ Hall,
    unsigned* __restrict__ flags,
    const float* __restrict__ Whh,
    __bf16* __restrict__ Whhb)
{
    if (blockIdx.x >= 128){
        const int n4 = G4 * HID / 4;
        for (int i = (blockIdx.x - 128) * 256 + threadIdx.x; i < n4; i += 64 * 256){
            float4 v = ((const float4*)Whh)[i];
            bf16x4 o = { (__bf16)v.x, (__bf16)v.y, (__bf16)v.z, (__bf16)v.w };
            ((bf16x4*)Whhb)[i] = o;
        }
        return;
    }
    if (blockIdx.x == 0) flags[threadIdx.x] = 0u;   // 256 u32: flags + done

    int id = blockIdx.x * 256 + threadIdx.x;   // 32768 = BATCH*HID
    int b = id >> 10, j = id & 1023;
    float s = blh[j];
    const float4* lr = (const float4*)(latent + (size_t)b * LAT);
    const float4* wr = (const float4*)(Wlh + (size_t)j * LAT);
    for (int k = 0; k < LAT / 4; ++k){
        float4 a = lr[k], w = wr[k];
        s += a.x * w.x + a.y * w.y + a.z * w.z + a.w * w.w;
    }
    h0[id] = (__bf16)s;
    Hall[(size_t)MROWS * HID + id] = (__bf16)0.0f;
}

// ---------------------------------------------------------------------------
// K1 (grid 32 x 40): y<32: xg = emb[tok]@W_ih^T + b_ih + b_hh.
// y>=32 (256 blocks): W_out fp32->bf16 (boundary-flushed before mega).
// ---------------------------------------------------------------------------
__global__ __launch_bounds__(256) void gemm_xg(
    const float* __restrict__ emb,
    const float* __restrict__ Wih,
    const int*   __restrict__ tok,
    float*       __restrict__ xg,
    const float* __restrict__ bih,
    const float* __restrict__ bhh,
    const float* __restrict__ Woutf,
    __bf16*      __restrict__ Woutb)
{
    if (blockIdx.y >= MPAD / 128){
        if (Woutb){
            const int n4 = VOCAB * HID / 4;
            int cb = (blockIdx.y - 32) * 32 + blockIdx.x;   // 0..255
            for (int i = cb * 256 + threadIdx.x; i < n4; i += 256 * 256){
                float4 v = ((const float4*)Woutf)[i];
                bf16x4 o = { (__bf16)v.x, (__bf16)v.y, (__bf16)v.z, (__bf16)v.w };
                ((bf16x4*)Woutb)[i] = o;
            }
        }
        return;
    }

    __shared__ __bf16 As[2][128 * 32];
    __shared__ __bf16 Bs[2][128 * 32];

    const int tid  = threadIdx.x;
    const int wid  = tid >> 6, lane = tid & 63;
    const int tile_n = blockIdx.x, tile_m = blockIdx.y;
    const int wr = wid >> 1, wc = wid & 1;

    f32x4 acc[4][4] = {};

    auto stage = [&](int kt, int buf){
        #pragma unroll
        for (int j = 0; j < 2; ++j){
            const int slot = tid + j * 256;
            const int row  = slot >> 2;
            const int kb   = kt * 32 + (slot & 3) * 8;
            {
                const int brow = tile_n * 128 + row;
                const float4* p = (const float4*)(Wih + (size_t)brow * EMB + kb);
                float4 u = p[0], v = p[1];
                bf16x8 w = { (__bf16)u.x, (__bf16)u.y, (__bf16)u.z, (__bf16)u.w,
                             (__bf16)v.x, (__bf16)v.y, (__bf16)v.z, (__bf16)v.w };
                *(bf16x8*)&Bs[buf][row * 32 + (slot & 3) * 8] = w;
            }
            {
                int r = tile_m * 128 + row;
                int rc = (r < MROWS) ? r : (MROWS - 1);
                int token = tok[(rc & 31) * 128 + (rc >> 5)];
                const float4* p = (const float4*)(emb + (size_t)token * EMB + kb);
                float4 u = p[0], v = p[1];
                bf16x8 w = { (__bf16)u.x, (__bf16)u.y, (__bf16)u.z, (__bf16)u.w,
                             (__bf16)v.x, (__bf16)v.y, (__bf16)v.z, (__bf16)v.w };
                *(bf16x8*)&As[buf][row * 32 + (slot & 3) * 8] = w;
            }
        }
    };

    const int KT = EMB / 32;
    stage(0, 0);
    for (int kt = 0; kt < KT; ++kt){
        const int buf = kt & 1;
        __syncthreads();
        if (kt + 1 < KT) stage(kt + 1, buf ^ 1);
        const __bf16* Abuf = As[buf];
        const __bf16* Bbuf = Bs[buf];
        const int ar = lane & 15, ko = (lane >> 4) * 8;
        bf16x8 av[4], bv[4];
        #pragma unroll
        for (int m = 0; m < 4; ++m)
            av[m] = *(const bf16x8*)&Abuf[(wr * 64 + m * 16 + ar) * 32 + ko];
        #pragma unroll
        for (int n = 0; n < 4; ++n)
            bv[n] = *(const bf16x8*)&Bbuf[(wc * 64 + n * 16 + ar) * 32 + ko];
        #pragma unroll
        for (int m = 0; m < 4; ++m)
            #pragma unroll
            for (int n = 0; n < 4; ++n)
                acc[m][n] = __builtin_amdgcn_mfma_f32_16x16x32_bf16(av[m], bv[n], acc[m][n], 0, 0, 0);
    }

    const int r0 = tile_m * 128 + wr * 64 + ((lane >> 4) << 2);
    const int c0 = tile_n * 128 + wc * 64 + (lane & 15);
    #pragma unroll
    for (int m = 0; m < 4; ++m){
        #pragma unroll
        for (int n = 0; n < 4; ++n){
            const int col = c0 + n * 16;
            float badd = bih[col] + bhh[col];
            #pragma unroll
            for (int q = 0; q < 4; ++q){
                int row = r0 + m * 16 + q;
                xg[(size_t)row * G4 + col] = acc[m][n][q] + badd;
            }
        }
    }
}

// ---------------------------------------------------------------------------
// Fallback logits GEMM (used when mega overlap is unavailable)
// ---------------------------------------------------------------------------
template<int BF16B>
__global__ __launch_bounds__(256) void gemm_logits(
    const __bf16* __restrict__ A,
    const float*  __restrict__ Bf,
    const __bf16* __restrict__ Bb,
    float*        __restrict__ C,
    const float*  __restrict__ bias)
{
    __shared__ __bf16 As[2][128 * 32];
    __shared__ __bf16 Bs[2][128 * 32];

    const int tid  = threadIdx.x;
    const int wid  = tid >> 6, lane = tid & 63;
    const int bid = blockIdx.x;
    const int s   = (bid & 7) * (NTM * NTN / 8) + (bid >> 3);
    const int g   = s / (8 * NTN), rem = s % (8 * NTN);
    const int tile_m = g * 8 + (rem & 7);
    const int tile_n = rem >> 3;
    const int wr = wid >> 1, wc = wid & 1;

    f32x4 acc[4][4] = {};

    auto stage = [&](int kt, int buf){
        const int kb = kt * 32 + (lane & 3) * 8;
        #pragma unroll
        for (int c2 = 0; c2 < 2; ++c2){
            int rA = tile_m * 128 + c2 * 64 + wid * 16 + (lane >> 2);
            gll16(&As[buf][c2 * 2048 + wid * 512], A + (size_t)rA * HID + kb);
            if constexpr (BF16B){
                int rB = tile_n * 128 + c2 * 64 + wid * 16 + (lane >> 2);
                gll16(&Bs[buf][c2 * 2048 + wid * 512], Bb + (size_t)rB * HID + kb);
            }
        }
        if constexpr (!BF16B){
            #pragma unroll
            for (int j = 0; j < 2; ++j){
                const int slot = tid + j * 256;
                const int row  = slot >> 2;
                const int kb2  = kt * 32 + (slot & 3) * 8;
                const int brow = tile_n * 128 + row;
                const float4* p = (const float4*)(Bf + (size_t)brow * HID + kb2);
                float4 u = p[0], v = p[1];
                bf16x8 w = { (__bf16)u.x, (__bf16)u.y, (__bf16)u.z, (__bf16)u.w,
                             (__bf16)v.x, (__bf16)v.y, (__bf16)v.z, (__bf16)v.w };
                *(bf16x8*)&Bs[buf][row * 32 + (slot & 3) * 8] = w;
            }
        }
    };

    const int KT = HID / 32;
    stage(0, 0);
    for (int kt = 0; kt < KT; ++kt){
        const int buf = kt & 1;
        __syncthreads();
        if (kt + 1 < KT) stage(kt + 1, buf ^ 1);
        const __bf16* Abuf = As[buf];
        const __bf16* Bbuf = Bs[buf];
        const int ar = lane & 15, ko = (lane >> 4) * 8;
        bf16x8 av[4], bv[4];
        #pragma unroll
        for (int m = 0; m < 4; ++m)
            av[m] = *(const bf16x8*)&Abuf[(wr * 64 + m * 16 + ar) * 32 + ko];
        #pragma unroll
        for (int n = 0; n < 4; ++n)
            bv[n] = *(const bf16x8*)&Bbuf[(wc * 64 + n * 16 + ar) * 32 + ko];
        #pragma unroll
        for (int m = 0; m < 4; ++m)
            #pragma unroll
            for (int n = 0; n < 4; ++n)
                acc[m][n] = __builtin_amdgcn_mfma_f32_16x16x32_bf16(av[m], bv[n], acc[m][n], 0, 0, 0);
    }

    const int r0 = tile_m * 128 + wr * 64 + ((lane >> 4) << 2);
    const int c0 = tile_n * 128 + wc * 64 + (lane & 15);
    #pragma unroll
    for (int m = 0; m < 4; ++m){
        #pragma unroll
        for (int n = 0; n < 4; ++n){
            const int col = c0 + n * 16;
            float badd = bias[col];
            #pragma unroll
            for (int q = 0; q < 4; ++q){
                int row = r0 + m * 16 + q;
                if (row < MROWS){
                    int t = row >> 5, b = row & 31;
                    __builtin_nontemporal_store(acc[m][n][q] + badd,
                        &C[((size_t)b * TSTEP + t) * VOCAB + col]);
                }
            }
        }
    }
}

// ---------------------------------------------------------------------------
// MEGA: cooperative, up to 896 blocks. LDS is a 32KB UNION of the two roles
// (lstm 16KB | gemm 32KB) so occupancy = 4 blocks/CU -> coop capacity 1024.
//   blocks 0..127   : LSTM (flag barrier; block0 publishes done=t+1)
//   blocks 128..895 : persistent logits GEMM; tile (tm,tn) waits
//                     done >= min(4*tm+4,127) then computes.
// ---------------------------------------------------------------------------
__global__ __launch_bounds__(256, 4) void mega_kernel(
    const float*  __restrict__ xg,
    __bf16*       __restrict__ Hall,
    __bf16*       __restrict__ hbuf,
    const __bf16* __restrict__ Whhb,
    unsigned*     __restrict__ flags,     // [0..127] flags, [160] done
    const __bf16* __restrict__ Woutb,     // nullptr -> gemm role inactive
    float*        __restrict__ C,
    const float*  __restrict__ bout)
{
    __shared__ __align__(16) char smem[32768];
    unsigned* done = flags + 160;

    if (blockIdx.x < NBLK){
        // ================= LSTM role (uses 16KB of smem) =================
        __builtin_amdgcn_s_setprio(3);
        float* lds_g = (float*)smem;               // [4][4][4][64]
        const int tid = threadIdx.x, wid = tid >> 6, lane = tid & 63;
        const int jb = blockIdx.x * 8;

        bf16x8 bfrag[2][8];
        {
            const int gl = lane & 15, ko = (lane >> 4) * 8;
            #pragma unroll
            for (int nt = 0; nt < 2; ++nt){
                int gg = nt * 16 + gl;
                const __bf16* base =
                    Whhb + (size_t)((gg >> 3) * HID + jb + (gg & 7)) * HID + wid * 256 + ko;
                #pragma unroll
                for (int ks = 0; ks < 8; ++ks)
                    bfrag[nt][ks] = *(const bf16x8*)(base + ks * 32);
            }
        }

        const int b2 = tid >> 2, up0 = (tid & 3) * 2;
        const int mt2 = b2 >> 4, r2 = b2 & 15, reg2 = r2 & 3, lb2 = (r2 >> 2) << 4;
        float cst[2] = {0.0f, 0.0f};

        const float* xq = xg + (size_t)b2 * G4 + jb + up0;
        float2 xv[4];
        if (tid < 128){
            #pragma unroll
            for (int g = 0; g < 4; ++g) xv[g] = *(const float2*)(xq + g * HID);
        }

        const size_t e0 = (size_t)(lane & 15) * HID + wid * 256 + (lane >> 4) * 8;

        for (int t = 0; t < TSTEP; ++t){
            unsigned long long* hq = (unsigned long long*)(hbuf + (size_t)(t & 1) * (BATCH * HID));
            union { unsigned long long q[2]; bf16x8 v; } xa[16];
            #pragma unroll
            for (int ks = 0; ks < 8; ++ks){
                size_t q0 = (e0 + (size_t)ks * 32) >> 2;
                size_t q1 = q0 + ((size_t)16 * HID >> 2);
                xa[ks].q[0]     = __hip_atomic_load(hq + q0,     __ATOMIC_RELAXED, __HIP_MEMORY_SCOPE_AGENT);
                xa[ks].q[1]     = __hip_atomic_load(hq + q0 + 1, __ATOMIC_RELAXED, __HIP_MEMORY_SCOPE_AGENT);
                xa[8 + ks].q[0] = __hip_atomic_load(hq + q1,     __ATOMIC_RELAXED, __HIP_MEMORY_SCOPE_AGENT);
                xa[8 + ks].q[1] = __hip_atomic_load(hq + q1 + 1, __ATOMIC_RELAXED, __HIP_MEMORY_SCOPE_AGENT);
            }
            f32x4 a00 = {}, a01 = {}, a10 = {}, a11 = {};
            #pragma unroll
            for (int ks = 0; ks < 8; ++ks){
                a00 = __builtin_amdgcn_mfma_f32_16x16x32_bf16(xa[ks].v,     bfrag[0][ks], a00, 0, 0, 0);
                a01 = __builtin_amdgcn_mfma_f32_16x16x32_bf16(xa[ks].v,     bfrag[1][ks], a01, 0, 0, 0);
                a10 = __builtin_amdgcn_mfma_f32_16x16x32_bf16(xa[8 + ks].v, bfrag[0][ks], a10, 0, 0, 0);
                a11 = __builtin_amdgcn_mfma_f32_16x16x32_bf16(xa[8 + ks].v, bfrag[1][ks], a11, 0, 0, 0);
            }
            #pragma unroll
            for (int q = 0; q < 4; ++q){
                lds_g[((0 * 4 + wid) * 4 + q) * 64 + lane] = a00[q];
                lds_g[((1 * 4 + wid) * 4 + q) * 64 + lane] = a01[q];
                lds_g[((2 * 4 + wid) * 4 + q) * 64 + lane] = a10[q];
                lds_g[((3 * 4 + wid) * 4 + q) * 64 + lane] = a11[q];
            }
            __syncthreads();

            if (tid < 128){
                const float* xn = xq + (size_t)(t + 1) * (BATCH * G4);
                float2 xnew[4];
                #pragma unroll
                for (int g = 0; g < 4; ++g) xnew[g] = *(const float2*)(xn + g * HID);

                float h2[2];
                #pragma unroll
                for (int du = 0; du < 2; ++du){
                    int u2 = up0 + du;
                    float gate[4];
                    #pragma unroll
                    for (int ty = 0; ty < 4; ++ty){
                        int gg = ty * 8 + u2;
                        int mtnt = mt2 * 2 + (gg >> 4);
                        int li = lb2 | (gg & 15);
                        float s = 0.0f;
                        #pragma unroll
                        for (int w = 0; w < 4; ++w)
                            s += lds_g[((mtnt * 4 + w) * 4 + reg2) * 64 + li];
                        gate[ty] = s;
                    }
                    float gi = gate[0] + ((du == 0) ? xv[0].x : xv[0].y);
                    float gf = gate[1] + ((du == 0) ? xv[1].x : xv[1].y);
                    float gc = gate[2] + ((du == 0) ? xv[2].x : xv[2].y);
                    float go = gate[3] + ((du == 0) ? xv[3].x : xv[3].y);
                    float c = sigf(gf) * cst[du] + sigf(gi) * tanhfast(gc);
                    cst[du] = c;
                    h2[du] = sigf(go) * tanhfast(c);
                }
                #pragma unroll
                for (int g = 0; g < 4; ++g) xv[g] = xnew[g];

                union { __bf16 h[2]; unsigned u; } pk;
                pk.h[0] = (__bf16)h2[0]; pk.h[1] = (__bf16)h2[1];
                unsigned* hw = (unsigned*)(hbuf + (size_t)((t + 1) & 1) * (BATCH * HID)
                                           + (size_t)b2 * HID + jb + up0);
                __hip_atomic_store(hw, pk.u, __ATOMIC_RELAXED, __HIP_MEMORY_SCOPE_AGENT);
                __hip_atomic_store((unsigned*)(Hall + ((size_t)t * BATCH + b2) * HID + jb + up0),
                                   pk.u, __ATOMIC_RELAXED, __HIP_MEMORY_SCOPE_AGENT);
            }

            // ---- device barrier + done publish ----
            __syncthreads();             // vmcnt(0): agent stores complete
            if (wid == 0){
                if (lane == 0)
                    __hip_atomic_store(&flags[blockIdx.x], (unsigned)(t + 1),
                                       __ATOMIC_RELAXED, __HIP_MEMORY_SCOPE_AGENT);
                const unsigned tgt = (unsigned)(t + 1);
                if (t + 1 < TSTEP || blockIdx.x == 0){
                    const unsigned long long* fq = (const unsigned long long*)flags;
                    for (;;){
                        unsigned long long v = __hip_atomic_load(&fq[lane],
                                      __ATOMIC_RELAXED, __HIP_MEMORY_SCOPE_AGENT);
                        if ((unsigned)v >= tgt && (unsigned)(v >> 32) >= tgt) break;
                        __builtin_amdgcn_s_sleep(1);
                    }
                    if (blockIdx.x == 0 && lane == 0)
                        __hip_atomic_store(done, tgt, __ATOMIC_RELAXED, __HIP_MEMORY_SCOPE_AGENT);
                }
            }
            __syncthreads();
        }
        return;
    }

    // ================= GEMM role (persistent logits workers) =================
    if (!Woutb) return;
    __bf16* As0 = (__bf16*)smem;                 // [2][128*32] = 16KB
    __bf16* Bs0 = (__bf16*)(smem + 16384);       // [2][128*32] = 16KB

    const int gid = blockIdx.x - NBLK;
    const int tid = threadIdx.x;
    const int wid = tid >> 6, lane = tid & 63;
    const int wr = wid >> 1, wc = wid & 1;
    unsigned seen = 0;

    for (int i = gid; i < NTM * NTN; i += NG){
        const int tm = i / NTN, tn = i - tm * NTN;
        const unsigned need = (unsigned)((tm * 4 + 4 > TSTEP) ? TSTEP : tm * 4 + 4);
        if (seen < need){
            for (;;){
                unsigned d = __hip_atomic_load(done, __ATOMIC_RELAXED, __HIP_MEMORY_SCOPE_AGENT);
                if (d >= need){ seen = d; break; }
                __builtin_amdgcn_s_sleep(32);
            }
        }

        f32x4 acc[4][4] = {};

        auto stage = [&](int kt, int buf){
            __bf16* Ad = As0 + buf * 4096;
            __bf16* Bd = Bs0 + buf * 4096;
            const int kb = kt * 32 + (lane & 3) * 8;
            #pragma unroll
            for (int c2 = 0; c2 < 2; ++c2){
                int rA = tm * 128 + c2 * 64 + wid * 16 + (lane >> 2);
                gll16(Ad + c2 * 2048 + wid * 512, Hall + (size_t)rA * HID + kb);
                int rB = tn * 128 + c2 * 64 + wid * 16 + (lane >> 2);
                gll16(Bd + c2 * 2048 + wid * 512, Woutb + (size_t)rB * HID + kb);
            }
        };

        const int KT = HID / 32;
        stage(0, 0);
        for (int kt = 0; kt < KT; ++kt){
            const int buf = kt & 1;
            __syncthreads();
            if (kt + 1 < KT) stage(kt + 1, buf ^ 1);
            const __bf16* Abuf = As0 + buf * 4096;
            const __bf16* Bbuf = Bs0 + buf * 4096;
            const int ar = lane & 15, ko = (lane >> 4) * 8;
            bf16x8 av[4], bv[4];
            #pragma unroll
            for (int m = 0; m < 4; ++m)
                av[m] = *(const bf16x8*)&Abuf[(wr * 64 + m * 16 + ar) * 32 + ko];
            #pragma unroll
            for (int n = 0; n < 4; ++n)
                bv[n] = *(const bf16x8*)&Bbuf[(wc * 64 + n * 16 + ar) * 32 + ko];
            #pragma unroll
            for (int m = 0; m < 4; ++m)
                #pragma unroll
                for (int n = 0; n < 4; ++n)
                    acc[m][n] = __builtin_amdgcn_mfma_f32_16x16x32_bf16(av[m], bv[n], acc[m][n], 0, 0, 0);
        }

        const int r0 = tm * 128 + wr * 64 + ((lane >> 4) << 2);
        const int c0 = tn * 128 + wc * 64 + (lane & 15);
        #pragma unroll
        for (int m = 0; m < 4; ++m){
            #pragma unroll
            for (int n = 0; n < 4; ++n){
                const int col = c0 + n * 16;
                float badd = bout[col];
                #pragma unroll
                for (int q = 0; q < 4; ++q){
                    int row = r0 + m * 16 + q;
                    if (row < MROWS){
                        int t = row >> 5, b = row & 31;
                        __builtin_nontemporal_store(acc[m][n][q] + badd,
                            &C[((size_t)b * TSTEP + t) * VOCAB + col]);
                    }
                }
            }
        }
        __syncthreads();   // all waves done with LDS before next tile's stage
    }
}

// ---------------------------------------------------------------------------
extern "C" void kernel_launch(void* const* d_in, const int* in_sizes, int n_in,
                              void* d_out, int out_size, void* d_ws, size_t ws_size,
                              hipStream_t stream)
{
    const float* latent = (const float*)d_in[0];
    const int*   tokens = (const int*)d_in[1];
    const float* emb    = (const float*)d_in[2];
    const float* Wlh    = (const float*)d_in[3];
    const float* blh    = (const float*)d_in[4];
    const float* Wih    = (const float*)d_in[5];
    const float* bih    = (const float*)d_in[6];
    const float* Whh    = (const float*)d_in[7];
    const float* bhh    = (const float*)d_in[8];
    const float* Wout   = (const float*)d_in[9];
    const float* bout   = (const float*)d_in[10];
    float* out = (float*)d_out;

    const size_t xg_b   = (size_t)MPAD * G4 * 4;        // 64 MiB
    const size_t hall_b = (size_t)MPAD * HID * 2;       // 8 MiB
    const size_t whh_b  = (size_t)G4 * HID * 2;         // 8 MiB
    const size_t wout_b = (size_t)VOCAB * HID * 2;      // 62.5 MiB
    const size_t hb_b   = (size_t)2 * BATCH * HID * 2;  // 128 KiB
    const size_t cnt_b  = 1024;                          // flags + done

    char* p = (char*)d_ws;
    const bool wsA = ws_size >= xg_b + hall_b + whh_b + wout_b + hb_b + cnt_b;
    const bool wsB = ws_size >= hall_b + whh_b + wout_b + hb_b + cnt_b;

    float* xg;
    if (wsA){ xg = (float*)p; p += xg_b; }
    else    { xg = (float*)d_out; }
    __bf16* Hall = (__bf16*)p; p += hall_b;
    __bf16* Whhb = (__bf16*)p; p += whh_b;
    __bf16* Woutb = nullptr;
    if (wsA || wsB){ Woutb = (__bf16*)p; p += wout_b; }
    __bf16* hbuf = (__bf16*)p; p += hb_b;
    unsigned* flags = (unsigned*)p; p += cnt_b;

    init_kernel<<<dim3(192), dim3(256), 0, stream>>>(
        latent, Wlh, blh, hbuf, Hall, flags, Whh, Whhb);

    gemm_xg<<<dim3(G4 / 128, MPAD / 128 + 8), dim3(256), 0, stream>>>(
        emb, Wih, tokens, xg, bih, bhh, Wout, Woutb);

    // overlap only when xg does NOT alias d_out (gemm writes d_out live)
    const __bf16* wob_mega = wsA ? Woutb : nullptr;
    const float*  xgc   = xg;
    __bf16*       hallp = Hall;
    __bf16*       hbp   = hbuf;
    const __bf16* whhp  = Whhb;
    unsigned*     flagp = flags;
    float*        outp  = out;
    const float*  boutp = bout;
    void* args[] = { (void*)&xgc, (void*)&hallp, (void*)&hbp, (void*)&whhp,
                     (void*)&flagp, (void*)&wob_mega, (void*)&outp, (void*)&boutp };
    hipError_t cerr = hipLaunchCooperativeKernel(
        (void*)mega_kernel, dim3(wsA ? NBLK + NG : NBLK), dim3(256), args, 0, stream);

    bool mega_gemm = wsA && (cerr == hipSuccess);
    if (cerr != hipSuccess){
        // capacity reject: LSTM-only cooperative launch (GEMM role disabled)
        const __bf16* wob_null = nullptr;
        void* args2[] = { (void*)&xgc, (void*)&hallp, (void*)&hbp, (void*)&whhp,
                          (void*)&flagp, (void*)&wob_null, (void*)&outp, (void*)&boutp };
        hipLaunchCooperativeKernel((void*)mega_kernel, dim3(NBLK), dim3(256),
                                   args2, 0, stream);
    }

    if (!mega_gemm){
        if (Woutb)
            gemm_logits<1><<<dim3(NTM * NTN), dim3(256), 0, stream>>>(
                Hall, (const float*)nullptr, Woutb, out, bout);
        else
            gemm_logits<0><<<dim3(NTM * NTN), dim3(256), 0, stream>>>(
                Hall, Wout, (const __bf16*)nullptr, out, bout);
    }
}

// Round 10
// 1522.189 us; speedup vs baseline: 1.0372x; 1.0372x over previous
//
#include <hip/hip_runtime.h>
#include <cstdint>

typedef __bf16 bf16x8 __attribute__((ext_vector_type(8)));
typedef __bf16 bf16x4 __attribute__((ext_vector_type(4)));
typedef float  f32x4  __attribute__((ext_vector_type(4)));

#define VOCAB 32000
#define EMB   512
#define HID   1024
#define LAT   512
#define BATCH 32
#define TSTEP 127          // T-1
#define MROWS 4064         // TSTEP*BATCH
#define MPAD  4096
#define G4    4096         // 4*HID
#define NBLK  128          // lstm worker blocks
#define NTM   32           // logits M tiles
#define NTN   250          // logits N tiles

__device__ __forceinline__ float sigf(float x){ return 1.0f / (1.0f + __expf(-x)); }
__device__ __forceinline__ float tanhfast(float x){
    float ax = fabsf(x);
    float e  = __expf(-2.0f * ax);
    float t  = (1.0f - e) / (1.0f + e);
    return copysignf(t, x);
}

// async global->LDS, 16B/lane; LDS base wave-uniform (HW adds lane*16)
__device__ __forceinline__ void gll16(void* lds, const void* gsrc){
    __builtin_amdgcn_global_load_lds(
        (const __attribute__((address_space(1))) unsigned int*)gsrc,
        (__attribute__((address_space(3))) unsigned int*)lds,
        16, 0, 0);
}

// ---------------------------------------------------------------------------
// K0 (grid 192): blocks 0..127: h0 = latent@W_lh^T + b_lh; zero Hall pads;
// zero flags. blocks 128..191: W_hh fp32->bf16 (boundary-flushed).
// ---------------------------------------------------------------------------
__global__ __launch_bounds__(256) void init_kernel(
    const float* __restrict__ latent,
    const float* __restrict__ Wlh,
    const float* __restrict__ blh,
    __bf16* __restrict__ h0,
    __bf16* __restrict__ Hall,
    unsigned* __restrict__ flags,
    const float* __restrict__ Whh,
    __bf16* __restrict__ Whhb)
{
    if (blockIdx.x >= 128){
        const int n4 = G4 * HID / 4;
        for (int i = (blockIdx.x - 128) * 256 + threadIdx.x; i < n4; i += 64 * 256){
            float4 v = ((const float4*)Whh)[i];
            bf16x4 o = { (__bf16)v.x, (__bf16)v.y, (__bf16)v.z, (__bf16)v.w };
            ((bf16x4*)Whhb)[i] = o;
        }
        return;
    }
    if (blockIdx.x == 0) flags[threadIdx.x] = 0u;   // 256 u32 zeroed

    int id = blockIdx.x * 256 + threadIdx.x;   // 32768 = BATCH*HID
    int b = id >> 10, j = id & 1023;
    float s = blh[j];
    const float4* lr = (const float4*)(latent + (size_t)b * LAT);
    const float4* wr = (const float4*)(Wlh + (size_t)j * LAT);
    for (int k = 0; k < LAT / 4; ++k){
        float4 a = lr[k], w = wr[k];
        s += a.x * w.x + a.y * w.y + a.z * w.z + a.w * w.w;
    }
    h0[id] = (__bf16)s;
    Hall[(size_t)MROWS * HID + id] = (__bf16)0.0f;  // pad rows 4064..4095
}

// ---------------------------------------------------------------------------
// K1: xg[r][4096] = emb[tok(r)] @ W_ih^T + b_ih + b_hh   (fp32 in, fp32 out)
// ---------------------------------------------------------------------------
__global__ __launch_bounds__(256) void gemm_xg(
    const float* __restrict__ emb,
    const float* __restrict__ Wih,
    const int*   __restrict__ tok,
    float*       __restrict__ xg,
    const float* __restrict__ bih,
    const float* __restrict__ bhh)
{
    __shared__ __bf16 As[2][128 * 32];
    __shared__ __bf16 Bs[2][128 * 32];

    const int tid  = threadIdx.x;
    const int wid  = tid >> 6, lane = tid & 63;
    const int tile_n = blockIdx.x, tile_m = blockIdx.y;
    const int wr = wid >> 1, wc = wid & 1;

    f32x4 acc[4][4] = {};

    auto stage = [&](int kt, int buf){
        #pragma unroll
        for (int j = 0; j < 2; ++j){
            const int slot = tid + j * 256;
            const int row  = slot >> 2;
            const int kb   = kt * 32 + (slot & 3) * 8;
            {
                const int brow = tile_n * 128 + row;
                const float4* p = (const float4*)(Wih + (size_t)brow * EMB + kb);
                float4 u = p[0], v = p[1];
                bf16x8 w = { (__bf16)u.x, (__bf16)u.y, (__bf16)u.z, (__bf16)u.w,
                             (__bf16)v.x, (__bf16)v.y, (__bf16)v.z, (__bf16)v.w };
                *(bf16x8*)&Bs[buf][row * 32 + (slot & 3) * 8] = w;
            }
            {
                int r = tile_m * 128 + row;
                int rc = (r < MROWS) ? r : (MROWS - 1);
                int token = tok[(rc & 31) * 128 + (rc >> 5)];   // tokens[b][t]
                const float4* p = (const float4*)(emb + (size_t)token * EMB + kb);
                float4 u = p[0], v = p[1];
                bf16x8 w = { (__bf16)u.x, (__bf16)u.y, (__bf16)u.z, (__bf16)u.w,
                             (__bf16)v.x, (__bf16)v.y, (__bf16)v.z, (__bf16)v.w };
                *(bf16x8*)&As[buf][row * 32 + (slot & 3) * 8] = w;
            }
        }
    };

    const int KT = EMB / 32;
    stage(0, 0);
    for (int kt = 0; kt < KT; ++kt){
        const int buf = kt & 1;
        __syncthreads();
        if (kt + 1 < KT) stage(kt + 1, buf ^ 1);
        const __bf16* Abuf = As[buf];
        const __bf16* Bbuf = Bs[buf];
        const int ar = lane & 15, ko = (lane >> 4) * 8;
        bf16x8 av[4], bv[4];
        #pragma unroll
        for (int m = 0; m < 4; ++m)
            av[m] = *(const bf16x8*)&Abuf[(wr * 64 + m * 16 + ar) * 32 + ko];
        #pragma unroll
        for (int n = 0; n < 4; ++n)
            bv[n] = *(const bf16x8*)&Bbuf[(wc * 64 + n * 16 + ar) * 32 + ko];
        #pragma unroll
        for (int m = 0; m < 4; ++m)
            #pragma unroll
            for (int n = 0; n < 4; ++n)
                acc[m][n] = __builtin_amdgcn_mfma_f32_16x16x32_bf16(av[m], bv[n], acc[m][n], 0, 0, 0);
    }

    const int r0 = tile_m * 128 + wr * 64 + ((lane >> 4) << 2);
    const int c0 = tile_n * 128 + wc * 64 + (lane & 15);
    #pragma unroll
    for (int m = 0; m < 4; ++m){
        #pragma unroll
        for (int n = 0; n < 4; ++n){
            const int col = c0 + n * 16;
            float badd = bih[col] + bhh[col];
            #pragma unroll
            for (int q = 0; q < 4; ++q){
                int row = r0 + m * 16 + q;
                xg[(size_t)row * G4 + col] = acc[m][n][q] + badd;
            }
        }
    }
}

// ---------------------------------------------------------------------------
// K3: logits = Hall @ W_out^T + b_out  (fp32 out, scattered to out[b][t][v])
// GROUP_M=8 super-tiles + bijective XCD swizzle (nwg=8000 % 8 == 0).
// ---------------------------------------------------------------------------
template<int BF16B>
__global__ __launch_bounds__(256) void gemm_logits(
    const __bf16* __restrict__ A,     // Hall, padded to MPAD rows, K=HID
    const float*  __restrict__ Bf,    // W_out fp32 (BF16B=0)
    const __bf16* __restrict__ Bb,    // W_out bf16 (BF16B=1)
    float*        __restrict__ C,
    const float*  __restrict__ bias)
{
    __shared__ __bf16 As[2][128 * 32];
    __shared__ __bf16 Bs[2][128 * 32];

    const int tid  = threadIdx.x;
    const int wid  = tid >> 6, lane = tid & 63;
    const int bid = blockIdx.x;
    const int s   = (bid & 7) * (NTM * NTN / 8) + (bid >> 3);
    const int g   = s / (8 * NTN), rem = s % (8 * NTN);
    const int tile_m = g * 8 + (rem & 7);
    const int tile_n = rem >> 3;
    const int wr = wid >> 1, wc = wid & 1;

    f32x4 acc[4][4] = {};

    auto stage = [&](int kt, int buf){
        const int kb = kt * 32 + (lane & 3) * 8;
        #pragma unroll
        for (int c2 = 0; c2 < 2; ++c2){
            int rA = tile_m * 128 + c2 * 64 + wid * 16 + (lane >> 2);
            gll16(&As[buf][c2 * 2048 + wid * 512], A + (size_t)rA * HID + kb);
            if constexpr (BF16B){
                int rB = tile_n * 128 + c2 * 64 + wid * 16 + (lane >> 2);
                gll16(&Bs[buf][c2 * 2048 + wid * 512], Bb + (size_t)rB * HID + kb);
            }
        }
        if constexpr (!BF16B){
            #pragma unroll
            for (int j = 0; j < 2; ++j){
                const int slot = tid + j * 256;
                const int row  = slot >> 2;
                const int kb2  = kt * 32 + (slot & 3) * 8;
                const int brow = tile_n * 128 + row;
                const float4* p = (const float4*)(Bf + (size_t)brow * HID + kb2);
                float4 u = p[0], v = p[1];
                bf16x8 w = { (__bf16)u.x, (__bf16)u.y, (__bf16)u.z, (__bf16)u.w,
                             (__bf16)v.x, (__bf16)v.y, (__bf16)v.z, (__bf16)v.w };
                *(bf16x8*)&Bs[buf][row * 32 + (slot & 3) * 8] = w;
            }
        }
    };

    const int KT = HID / 32;
    stage(0, 0);
    for (int kt = 0; kt < KT; ++kt){
        const int buf = kt & 1;
        __syncthreads();                 // drains vmcnt (gll) + lgkmcnt
        if (kt + 1 < KT) stage(kt + 1, buf ^ 1);
        const __bf16* Abuf = As[buf];
        const __bf16* Bbuf = Bs[buf];
        const int ar = lane & 15, ko = (lane >> 4) * 8;
        bf16x8 av[4], bv[4];
        #pragma unroll
        for (int m = 0; m < 4; ++m)
            av[m] = *(const bf16x8*)&Abuf[(wr * 64 + m * 16 + ar) * 32 + ko];
        #pragma unroll
        for (int n = 0; n < 4; ++n)
            bv[n] = *(const bf16x8*)&Bbuf[(wc * 64 + n * 16 + ar) * 32 + ko];
        #pragma unroll
        for (int m = 0; m < 4; ++m)
            #pragma unroll
            for (int n = 0; n < 4; ++n)
                acc[m][n] = __builtin_amdgcn_mfma_f32_16x16x32_bf16(av[m], bv[n], acc[m][n], 0, 0, 0);
    }

    const int r0 = tile_m * 128 + wr * 64 + ((lane >> 4) << 2);
    const int c0 = tile_n * 128 + wc * 64 + (lane & 15);
    #pragma unroll
    for (int m = 0; m < 4; ++m){
        #pragma unroll
        for (int n = 0; n < 4; ++n){
            const int col = c0 + n * 16;
            float badd = bias[col];
            #pragma unroll
            for (int q = 0; q < 4; ++q){
                int row = r0 + m * 16 + q;
                if (row < MROWS){
                    int t = row >> 5, b = row & 31;
                    __builtin_nontemporal_store(acc[m][n][q] + badd,
                        &C[((size_t)b * TSTEP + t) * VOCAB + col]);
                }
            }
        }
    }
}

// ---------------------------------------------------------------------------
// K2: 127 LSTM steps, ONE cooperative kernel (256 blocks):
//   blocks 0..127   : LSTM; h read from Hall[t-1] (h0 at t=0), SINGLE agent
//                     store to Hall[t] per thread per step (halved drain).
//   blocks 128..255 : W_out fp32->bf16 under the lstm shadow, then exit.
// Barrier: per-block contiguous flag store + wave0 coalesced u64 poll.
// ---------------------------------------------------------------------------
__global__ __launch_bounds__(256) void lstm_coop(
    const float*  __restrict__ xg,
    __bf16*       __restrict__ Hall,
    const __bf16* __restrict__ h0,
    const __bf16* __restrict__ Whhb,
    unsigned*     __restrict__ flags,
    const float*  __restrict__ Woutf,
    __bf16*       __restrict__ Woutb)
{
    if (blockIdx.x >= NBLK){
        if (Woutb){
            const int n4 = VOCAB * HID / 4;          // 8.192M float4
            for (int i = (blockIdx.x - NBLK) * 256 + threadIdx.x; i < n4; i += NBLK * 256){
                float4 v = ((const float4*)Woutf)[i];
                bf16x4 o = { (__bf16)v.x, (__bf16)v.y, (__bf16)v.z, (__bf16)v.w };
                ((bf16x4*)Woutb)[i] = o;
            }
        }
        return;
    }

    __shared__ float lds_g[4 * 4 * 4 * 64];    // [acc][wid][reg][lane] = 16KB
    const int tid = threadIdx.x, wid = tid >> 6, lane = tid & 63;
    const int jb = blockIdx.x * 8;

    // W_hh fragments for our 32 gate cols, this wave's K-quarter (64 VGPRs)
    bf16x8 bfrag[2][8];
    {
        const int gl = lane & 15, ko = (lane >> 4) * 8;
        #pragma unroll
        for (int nt = 0; nt < 2; ++nt){
            int gg = nt * 16 + gl;                     // type=gg>>3, unit=gg&7
            const __bf16* base =
                Whhb + (size_t)((gg >> 3) * HID + jb + (gg & 7)) * HID + wid * 256 + ko;
            #pragma unroll
            for (int ks = 0; ks < 8; ++ks)
                bfrag[nt][ks] = *(const bf16x8*)(base + ks * 32);
        }
    }

    // update-phase ownership: tid<128, 2 units each -> 4B-packed h stores
    const int b2 = tid >> 2, up0 = (tid & 3) * 2;
    const int mt2 = b2 >> 4, r2 = b2 & 15, reg2 = r2 & 3, lb2 = (r2 >> 2) << 4;
    float cst[2] = {0.0f, 0.0f};

    const float* xq = xg + (size_t)b2 * G4 + jb + up0;
    float2 xv[4];
    if (tid < 128){
        #pragma unroll
        for (int g = 0; g < 4; ++g) xv[g] = *(const float2*)(xq + g * HID);
    }

    const size_t e0 = (size_t)(lane & 15) * HID + wid * 256 + (lane >> 4) * 8; // elems

    for (int t = 0; t < TSTEP; ++t){
        // ---- h source: h0 at t=0, else Hall[t-1] (same [b][HID] layout) ----
        const __bf16* hsrc = (t == 0) ? h0 : (Hall + (size_t)(t - 1) * (BATCH * HID));
        const unsigned long long* hq = (const unsigned long long*)hsrc;
        union { unsigned long long q[2]; bf16x8 v; } xa[16];
        #pragma unroll
        for (int ks = 0; ks < 8; ++ks){
            size_t q0 = (e0 + (size_t)ks * 32) >> 2;
            size_t q1 = q0 + ((size_t)16 * HID >> 2);
            xa[ks].q[0]     = __hip_atomic_load(hq + q0,     __ATOMIC_RELAXED, __HIP_MEMORY_SCOPE_AGENT);
            xa[ks].q[1]     = __hip_atomic_load(hq + q0 + 1, __ATOMIC_RELAXED, __HIP_MEMORY_SCOPE_AGENT);
            xa[8 + ks].q[0] = __hip_atomic_load(hq + q1,     __ATOMIC_RELAXED, __HIP_MEMORY_SCOPE_AGENT);
            xa[8 + ks].q[1] = __hip_atomic_load(hq + q1 + 1, __ATOMIC_RELAXED, __HIP_MEMORY_SCOPE_AGENT);
        }
        f32x4 a00 = {}, a01 = {}, a10 = {}, a11 = {};
        #pragma unroll
        for (int ks = 0; ks < 8; ++ks){
            a00 = __builtin_amdgcn_mfma_f32_16x16x32_bf16(xa[ks].v,     bfrag[0][ks], a00, 0, 0, 0);
            a01 = __builtin_amdgcn_mfma_f32_16x16x32_bf16(xa[ks].v,     bfrag[1][ks], a01, 0, 0, 0);
            a10 = __builtin_amdgcn_mfma_f32_16x16x32_bf16(xa[8 + ks].v, bfrag[0][ks], a10, 0, 0, 0);
            a11 = __builtin_amdgcn_mfma_f32_16x16x32_bf16(xa[8 + ks].v, bfrag[1][ks], a11, 0, 0, 0);
        }
        #pragma unroll
        for (int q = 0; q < 4; ++q){
            lds_g[((0 * 4 + wid) * 4 + q) * 64 + lane] = a00[q];
            lds_g[((1 * 4 + wid) * 4 + q) * 64 + lane] = a01[q];
            lds_g[((2 * 4 + wid) * 4 + q) * 64 + lane] = a10[q];
            lds_g[((3 * 4 + wid) * 4 + q) * 64 + lane] = a11[q];
        }
        __syncthreads();

        // ---- update phase: 128 threads, 2 units each ----
        if (tid < 128){
            // issue next-step xg prefetch FIRST (overlaps LDS reduce + math)
            const float* xn = xq + (size_t)(t + 1) * (BATCH * G4);
            float2 xnew[4];
            #pragma unroll
            for (int g = 0; g < 4; ++g) xnew[g] = *(const float2*)(xn + g * HID);

            float h2[2];
            #pragma unroll
            for (int du = 0; du < 2; ++du){
                int u2 = up0 + du;
                float gate[4];
                #pragma unroll
                for (int ty = 0; ty < 4; ++ty){
                    int gg = ty * 8 + u2;
                    int mtnt = mt2 * 2 + (gg >> 4);
                    int li = lb2 | (gg & 15);
                    float s = 0.0f;
                    #pragma unroll
                    for (int w = 0; w < 4; ++w)
                        s += lds_g[((mtnt * 4 + w) * 4 + reg2) * 64 + li];
                    gate[ty] = s;
                }
                float gi = gate[0] + ((du == 0) ? xv[0].x : xv[0].y);
                float gf = gate[1] + ((du == 0) ? xv[1].x : xv[1].y);
                float gc = gate[2] + ((du == 0) ? xv[2].x : xv[2].y);
                float go = gate[3] + ((du == 0) ? xv[3].x : xv[3].y);
                float c = sigf(gf) * cst[du] + sigf(gi) * tanhfast(gc);
                cst[du] = c;
                h2[du] = sigf(go) * tanhfast(c);
            }
            #pragma unroll
            for (int g = 0; g < 4; ++g) xv[g] = xnew[g];

            union { __bf16 h[2]; unsigned u; } pk;
            pk.h[0] = (__bf16)h2[0]; pk.h[1] = (__bf16)h2[1];
            // SINGLE h store per thread per step (Hall doubles as h ping buffer)
            __hip_atomic_store((unsigned*)(Hall + ((size_t)t * BATCH + b2) * HID + jb + up0),
                               pk.u, __ATOMIC_RELAXED, __HIP_MEMORY_SCOPE_AGENT);
        }

        if (t + 1 == TSTEP) break;       // Hall flushed at kernel-end boundary

        // ---- device barrier: per-block flag store + coalesced u64 poll ----
        __syncthreads();                 // vmcnt(0): h agent store COMPLETE
        if (wid == 0){
            if (lane == 0){
                __hip_atomic_store(&flags[blockIdx.x], (unsigned)(t + 1),
                                   __ATOMIC_RELAXED, __HIP_MEMORY_SCOPE_AGENT);
            }
            const unsigned tgt = (unsigned)(t + 1);
            const unsigned long long* fq = (const unsigned long long*)flags;
            for (;;){
                unsigned long long v = __hip_atomic_load(&fq[lane],
                              __ATOMIC_RELAXED, __HIP_MEMORY_SCOPE_AGENT);
                if ((unsigned)v >= tgt && (unsigned)(v >> 32) >= tgt) break;
                __builtin_amdgcn_s_sleep(1);
            }
        }
        __syncthreads();
    }
}

// ---------------------------------------------------------------------------
extern "C" void kernel_launch(void* const* d_in, const int* in_sizes, int n_in,
                              void* d_out, int out_size, void* d_ws, size_t ws_size,
                              hipStream_t stream)
{
    const float* latent = (const float*)d_in[0];
    const int*   tokens = (const int*)d_in[1];
    const float* emb    = (const float*)d_in[2];
    const float* Wlh    = (const float*)d_in[3];
    const float* blh    = (const float*)d_in[4];
    const float* Wih    = (const float*)d_in[5];
    const float* bih    = (const float*)d_in[6];
    const float* Whh    = (const float*)d_in[7];
    const float* bhh    = (const float*)d_in[8];
    const float* Wout   = (const float*)d_in[9];
    const float* bout   = (const float*)d_in[10];
    float* out = (float*)d_out;

    const size_t xg_b   = (size_t)MPAD * G4 * 4;        // 64 MiB fp32 gate preacts
    const size_t hall_b = (size_t)MPAD * HID * 2;       // 8 MiB bf16
    const size_t whh_b  = (size_t)G4 * HID * 2;         // 8 MiB bf16
    const size_t wout_b = (size_t)VOCAB * HID * 2;      // 62.5 MiB bf16
    const size_t h0_b   = (size_t)BATCH * HID * 2;      // 64 KiB
    const size_t cnt_b  = 1024;                          // 256 u32 flags

    char* p = (char*)d_ws;
    const bool wsA = ws_size >= xg_b + hall_b + whh_b + wout_b + h0_b + cnt_b;
    const bool wsB = ws_size >= hall_b + whh_b + wout_b + h0_b + cnt_b;

    float* xg;
    if (wsA){ xg = (float*)p; p += xg_b; }
    else    { xg = (float*)d_out; }      // 64 MiB scratch; consumed before K3 writes
    __bf16* Hall = (__bf16*)p; p += hall_b;
    __bf16* Whhb = (__bf16*)p; p += whh_b;
    __bf16* Woutb = nullptr;
    if (wsA || wsB){ Woutb = (__bf16*)p; p += wout_b; }
    __bf16* h0 = (__bf16*)p; p += h0_b;
    unsigned* flags = (unsigned*)p; p += cnt_b;

    init_kernel<<<dim3(192), dim3(256), 0, stream>>>(
        latent, Wlh, blh, h0, Hall, flags, Whh, Whhb);

    gemm_xg<<<dim3(G4 / 128, MPAD / 128), dim3(256), 0, stream>>>(
        emb, Wih, tokens, xg, bih, bhh);

    {
        const float*  xgc   = xg;
        __bf16*       hallp = Hall;
        const __bf16* h0p   = h0;
        const __bf16* whhp  = Whhb;
        unsigned*     flagp = flags;
        const float*  wof   = Wout;
        __bf16*       wob   = Woutb;
        void* args[] = { (void*)&xgc, (void*)&hallp, (void*)&h0p, (void*)&whhp,
                         (void*)&flagp, (void*)&wof, (void*)&wob };
        hipLaunchCooperativeKernel((void*)lstm_coop, dim3(2 * NBLK), dim3(256),
                                   args, 0, stream);
    }

    if (Woutb)
        gemm_logits<1><<<dim3(NTM * NTN), dim3(256), 0, stream>>>(
            Hall, (const float*)nullptr, Woutb, out, bout);
    else
        gemm_logits<0><<<dim3(NTM * NTN), dim3(256), 0, stream>>>(
            Hall, Wout, (const __bf16*)nullptr, out, bout);
}

// Round 11
// 1413.319 us; speedup vs baseline: 1.1171x; 1.0770x over previous
//
#include <hip/hip_runtime.h>
#include <cstdint>

typedef __bf16 bf16x8 __attribute__((ext_vector_type(8)));
typedef __bf16 bf16x4 __attribute__((ext_vector_type(4)));
typedef float  f32x4  __attribute__((ext_vector_type(4)));

#define VOCAB 32000
#define EMB   512
#define HID   1024
#define LAT   512
#define BATCH 32
#define TSTEP 127          // T-1
#define MROWS 4064         // TSTEP*BATCH
#define MPAD  4096
#define G4    4096         // 4*HID
#define NBLK  128          // lstm worker blocks
#define NTM   32           // logits M tiles
#define NTN   250          // logits N tiles

__device__ __forceinline__ float sigf(float x){ return 1.0f / (1.0f + __expf(-x)); }
__device__ __forceinline__ float tanhfast(float x){
    float ax = fabsf(x);
    float e  = __expf(-2.0f * ax);
    float t  = (1.0f - e) / (1.0f + e);
    return copysignf(t, x);
}

// async global->LDS, 16B/lane; LDS base wave-uniform (HW adds lane*16)
__device__ __forceinline__ void gll16(void* lds, const void* gsrc){
    __builtin_amdgcn_global_load_lds(
        (const __attribute__((address_space(1))) unsigned int*)gsrc,
        (__attribute__((address_space(3))) unsigned int*)lds,
        16, 0, 0);
}

// ---------------------------------------------------------------------------
// K0 (grid 192): blocks 0..127: h0 = latent@W_lh^T + b_lh -> hbuf[0]; zero
// Hall pad rows; zero flags. blocks 128..191: W_hh fp32->bf16.
// ---------------------------------------------------------------------------
__global__ __launch_bounds__(256) void init_kernel(
    const float* __restrict__ latent,
    const float* __restrict__ Wlh,
    const float* __restrict__ blh,
    __bf16* __restrict__ h0,
    __bf16* __restrict__ Hall,
    unsigned* __restrict__ flags,
    const float* __restrict__ Whh,
    __bf16* __restrict__ Whhb)
{
    if (blockIdx.x >= 128){
        const int n4 = G4 * HID / 4;
        for (int i = (blockIdx.x - 128) * 256 + threadIdx.x; i < n4; i += 64 * 256){
            float4 v = ((const float4*)Whh)[i];
            bf16x4 o = { (__bf16)v.x, (__bf16)v.y, (__bf16)v.z, (__bf16)v.w };
            ((bf16x4*)Whhb)[i] = o;
        }
        return;
    }
    if (blockIdx.x == 0) flags[threadIdx.x] = 0u;   // 256 u32 zeroed (contiguous)

    int id = blockIdx.x * 256 + threadIdx.x;   // 32768 = BATCH*HID
    int b = id >> 10, j = id & 1023;
    float s = blh[j];
    const float4* lr = (const float4*)(latent + (size_t)b * LAT);
    const float4* wr = (const float4*)(Wlh + (size_t)j * LAT);
    for (int k = 0; k < LAT / 4; ++k){
        float4 a = lr[k], w = wr[k];
        s += a.x * w.x + a.y * w.y + a.z * w.z + a.w * w.w;
    }
    h0[id] = (__bf16)s;                         // hbuf[0][b][j]
    Hall[(size_t)MROWS * HID + id] = (__bf16)0.0f;  // pad rows 4064..4095
}

// ---------------------------------------------------------------------------
// K1: xg[r][4096] = emb[tok(r)] @ W_ih^T + b_ih + b_hh   (fp32 in, fp32 out)
// ---------------------------------------------------------------------------
__global__ __launch_bounds__(256) void gemm_xg(
    const float* __restrict__ emb,
    const float* __restrict__ Wih,
    const int*   __restrict__ tok,
    float*       __restrict__ xg,
    const float* __restrict__ bih,
    const float* __restrict__ bhh)
{
    __shared__ __bf16 As[2][128 * 32];
    __shared__ __bf16 Bs[2][128 * 32];

    const int tid  = threadIdx.x;
    const int wid  = tid >> 6, lane = tid & 63;
    const int tile_n = blockIdx.x, tile_m = blockIdx.y;
    const int wr = wid >> 1, wc = wid & 1;

    f32x4 acc[4][4] = {};

    auto stage = [&](int kt, int buf){
        #pragma unroll
        for (int j = 0; j < 2; ++j){
            const int slot = tid + j * 256;
            const int row  = slot >> 2;
            const int kb   = kt * 32 + (slot & 3) * 8;
            {
                const int brow = tile_n * 128 + row;
                const float4* p = (const float4*)(Wih + (size_t)brow * EMB + kb);
                float4 u = p[0], v = p[1];
                bf16x8 w = { (__bf16)u.x, (__bf16)u.y, (__bf16)u.z, (__bf16)u.w,
                             (__bf16)v.x, (__bf16)v.y, (__bf16)v.z, (__bf16)v.w };
                *(bf16x8*)&Bs[buf][row * 32 + (slot & 3) * 8] = w;
            }
            {
                int r = tile_m * 128 + row;
                int rc = (r < MROWS) ? r : (MROWS - 1);
                int token = tok[(rc & 31) * 128 + (rc >> 5)];   // tokens[b][t]
                const float4* p = (const float4*)(emb + (size_t)token * EMB + kb);
                float4 u = p[0], v = p[1];
                bf16x8 w = { (__bf16)u.x, (__bf16)u.y, (__bf16)u.z, (__bf16)u.w,
                             (__bf16)v.x, (__bf16)v.y, (__bf16)v.z, (__bf16)v.w };
                *(bf16x8*)&As[buf][row * 32 + (slot & 3) * 8] = w;
            }
        }
    };

    const int KT = EMB / 32;
    stage(0, 0);
    for (int kt = 0; kt < KT; ++kt){
        const int buf = kt & 1;
        __syncthreads();
        if (kt + 1 < KT) stage(kt + 1, buf ^ 1);
        const __bf16* Abuf = As[buf];
        const __bf16* Bbuf = Bs[buf];
        const int ar = lane & 15, ko = (lane >> 4) * 8;
        bf16x8 av[4], bv[4];
        #pragma unroll
        for (int m = 0; m < 4; ++m)
            av[m] = *(const bf16x8*)&Abuf[(wr * 64 + m * 16 + ar) * 32 + ko];
        #pragma unroll
        for (int n = 0; n < 4; ++n)
            bv[n] = *(const bf16x8*)&Bbuf[(wc * 64 + n * 16 + ar) * 32 + ko];
        #pragma unroll
        for (int m = 0; m < 4; ++m)
            #pragma unroll
            for (int n = 0; n < 4; ++n)
                acc[m][n] = __builtin_amdgcn_mfma_f32_16x16x32_bf16(av[m], bv[n], acc[m][n], 0, 0, 0);
    }

    const int r0 = tile_m * 128 + wr * 64 + ((lane >> 4) << 2);
    const int c0 = tile_n * 128 + wc * 64 + (lane & 15);
    #pragma unroll
    for (int m = 0; m < 4; ++m){
        #pragma unroll
        for (int n = 0; n < 4; ++n){
            const int col = c0 + n * 16;
            float badd = bih[col] + bhh[col];
            #pragma unroll
            for (int q = 0; q < 4; ++q){
                int row = r0 + m * 16 + q;
                xg[(size_t)row * G4 + col] = acc[m][n][q] + badd;
            }
        }
    }
}

// ---------------------------------------------------------------------------
// K3: logits = Hall @ W_out^T + b_out  (fp32 out, scattered to out[b][t][v])
// GROUP_M=8 super-tiles + bijective XCD swizzle (nwg=8000 % 8 == 0).
// ---------------------------------------------------------------------------
template<int BF16B>
__global__ __launch_bounds__(256) void gemm_logits(
    const __bf16* __restrict__ A,     // Hall, padded to MPAD rows, K=HID
    const float*  __restrict__ Bf,    // W_out fp32 (BF16B=0)
    const __bf16* __restrict__ Bb,    // W_out bf16 (BF16B=1)
    float*        __restrict__ C,
    const float*  __restrict__ bias)
{
    __shared__ __bf16 As[2][128 * 32];
    __shared__ __bf16 Bs[2][128 * 32];

    const int tid  = threadIdx.x;
    const int wid  = tid >> 6, lane = tid & 63;
    const int bid = blockIdx.x;
    const int s   = (bid & 7) * (NTM * NTN / 8) + (bid >> 3);
    const int g   = s / (8 * NTN), rem = s % (8 * NTN);
    const int tile_m = g * 8 + (rem & 7);
    const int tile_n = rem >> 3;
    const int wr = wid >> 1, wc = wid & 1;

    f32x4 acc[4][4] = {};

    auto stage = [&](int kt, int buf){
        const int kb = kt * 32 + (lane & 3) * 8;
        #pragma unroll
        for (int c2 = 0; c2 < 2; ++c2){
            int rA = tile_m * 128 + c2 * 64 + wid * 16 + (lane >> 2);
            gll16(&As[buf][c2 * 2048 + wid * 512], A + (size_t)rA * HID + kb);
            if constexpr (BF16B){
                int rB = tile_n * 128 + c2 * 64 + wid * 16 + (lane >> 2);
                gll16(&Bs[buf][c2 * 2048 + wid * 512], Bb + (size_t)rB * HID + kb);
            }
        }
        if constexpr (!BF16B){
            #pragma unroll
            for (int j = 0; j < 2; ++j){
                const int slot = tid + j * 256;
                const int row  = slot >> 2;
                const int kb2  = kt * 32 + (slot & 3) * 8;
                const int brow = tile_n * 128 + row;
                const float4* p = (const float4*)(Bf + (size_t)brow * HID + kb2);
                float4 u = p[0], v = p[1];
                bf16x8 w = { (__bf16)u.x, (__bf16)u.y, (__bf16)u.z, (__bf16)u.w,
                             (__bf16)v.x, (__bf16)v.y, (__bf16)v.z, (__bf16)v.w };
                *(bf16x8*)&Bs[buf][row * 32 + (slot & 3) * 8] = w;
            }
        }
    };

    const int KT = HID / 32;
    stage(0, 0);
    for (int kt = 0; kt < KT; ++kt){
        const int buf = kt & 1;
        __syncthreads();                 // drains vmcnt (gll) + lgkmcnt
        if (kt + 1 < KT) stage(kt + 1, buf ^ 1);
        const __bf16* Abuf = As[buf];
        const __bf16* Bbuf = Bs[buf];
        const int ar = lane & 15, ko = (lane >> 4) * 8;
        bf16x8 av[4], bv[4];
        #pragma unroll
        for (int m = 0; m < 4; ++m)
            av[m] = *(const bf16x8*)&Abuf[(wr * 64 + m * 16 + ar) * 32 + ko];
        #pragma unroll
        for (int n = 0; n < 4; ++n)
            bv[n] = *(const bf16x8*)&Bbuf[(wc * 64 + n * 16 + ar) * 32 + ko];
        #pragma unroll
        for (int m = 0; m < 4; ++m)
            #pragma unroll
            for (int n = 0; n < 4; ++n)
                acc[m][n] = __builtin_amdgcn_mfma_f32_16x16x32_bf16(av[m], bv[n], acc[m][n], 0, 0, 0);
    }

    const int r0 = tile_m * 128 + wr * 64 + ((lane >> 4) << 2);
    const int c0 = tile_n * 128 + wc * 64 + (lane & 15);
    #pragma unroll
    for (int m = 0; m < 4; ++m){
        #pragma unroll
        for (int n = 0; n < 4; ++n){
            const int col = c0 + n * 16;
            float badd = bias[col];
            #pragma unroll
            for (int q = 0; q < 4; ++q){
                int row = r0 + m * 16 + q;
                if (row < MROWS){
                    int t = row >> 5, b = row & 31;
                    __builtin_nontemporal_store(acc[m][n][q] + badd,
                        &C[((size_t)b * TSTEP + t) * VOCAB + col]);
                }
            }
        }
    }
}

// ---------------------------------------------------------------------------
// K2: 127 LSTM steps, ONE cooperative kernel (256 blocks):
//   blocks 0..127   : LSTM. h exchange via SMALL hbuf ping-pong (agent
//                     atomics, hot at coherence point). Hall plain-store is
//                     DEFERRED past the drain (fire-and-forget during poll).
//   blocks 128..255 : W_out fp32->bf16 under the lstm shadow, then exit.
// Barrier: contiguous per-block flag store + wave0 coalesced u64 poll.
// ---------------------------------------------------------------------------
__global__ __launch_bounds__(256) void lstm_coop(
    const float*  __restrict__ xg,
    __bf16*       __restrict__ Hall,
    __bf16*       __restrict__ hbuf,    // 2 * BATCH*HID ping-pong, [0]=h0
    const __bf16* __restrict__ Whhb,
    unsigned*     __restrict__ flags,   // 128 contiguous u32
    const float*  __restrict__ Woutf,
    __bf16*       __restrict__ Woutb)
{
    if (blockIdx.x >= NBLK){
        if (Woutb){
            const int n4 = VOCAB * HID / 4;          // 8.192M float4
            for (int i = (blockIdx.x - NBLK) * 256 + threadIdx.x; i < n4; i += NBLK * 256){
                float4 v = ((const float4*)Woutf)[i];
                bf16x4 o = { (__bf16)v.x, (__bf16)v.y, (__bf16)v.z, (__bf16)v.w };
                ((bf16x4*)Woutb)[i] = o;
            }
        }
        return;
    }

    __shared__ float lds_g[4 * 4 * 4 * 64];    // [acc][wid][reg][lane] = 16KB
    const int tid = threadIdx.x, wid = tid >> 6, lane = tid & 63;
    const int jb = blockIdx.x * 8;

    // W_hh fragments for our 32 gate cols, this wave's K-quarter (64 VGPRs)
    bf16x8 bfrag[2][8];
    {
        const int gl = lane & 15, ko = (lane >> 4) * 8;
        #pragma unroll
        for (int nt = 0; nt < 2; ++nt){
            int gg = nt * 16 + gl;                     // type=gg>>3, unit=gg&7
            const __bf16* base =
                Whhb + (size_t)((gg >> 3) * HID + jb + (gg & 7)) * HID + wid * 256 + ko;
            #pragma unroll
            for (int ks = 0; ks < 8; ++ks)
                bfrag[nt][ks] = *(const bf16x8*)(base + ks * 32);
        }
    }

    // update-phase ownership: tid<128, 2 units each -> 4B-packed h stores
    const int b2 = tid >> 2, up0 = (tid & 3) * 2;
    const int mt2 = b2 >> 4, r2 = b2 & 15, reg2 = r2 & 3, lb2 = (r2 >> 2) << 4;
    float cst[2] = {0.0f, 0.0f};

    const float* xq = xg + (size_t)b2 * G4 + jb + up0;
    float2 xv[4];
    if (tid < 128){
        #pragma unroll
        for (int g = 0; g < 4; ++g) xv[g] = *(const float2*)(xq + g * HID);
    }

    const size_t e0 = (size_t)(lane & 15) * HID + wid * 256 + (lane >> 4) * 8; // elems

    for (int t = 0; t < TSTEP; ++t){
        // ---- batched h loads from hot hbuf window (agent atomics) ----
        const unsigned long long* hq =
            (const unsigned long long*)(hbuf + (size_t)(t & 1) * (BATCH * HID));
        union { unsigned long long q[2]; bf16x8 v; } xa[16];
        #pragma unroll
        for (int ks = 0; ks < 8; ++ks){
            size_t q0 = (e0 + (size_t)ks * 32) >> 2;
            size_t q1 = q0 + ((size_t)16 * HID >> 2);
            xa[ks].q[0]     = __hip_atomic_load(hq + q0,     __ATOMIC_RELAXED, __HIP_MEMORY_SCOPE_AGENT);
            xa[ks].q[1]     = __hip_atomic_load(hq + q0 + 1, __ATOMIC_RELAXED, __HIP_MEMORY_SCOPE_AGENT);
            xa[8 + ks].q[0] = __hip_atomic_load(hq + q1,     __ATOMIC_RELAXED, __HIP_MEMORY_SCOPE_AGENT);
            xa[8 + ks].q[1] = __hip_atomic_load(hq + q1 + 1, __ATOMIC_RELAXED, __HIP_MEMORY_SCOPE_AGENT);
        }
        f32x4 a00 = {}, a01 = {}, a10 = {}, a11 = {};
        #pragma unroll
        for (int ks = 0; ks < 8; ++ks){
            a00 = __builtin_amdgcn_mfma_f32_16x16x32_bf16(xa[ks].v,     bfrag[0][ks], a00, 0, 0, 0);
            a01 = __builtin_amdgcn_mfma_f32_16x16x32_bf16(xa[ks].v,     bfrag[1][ks], a01, 0, 0, 0);
            a10 = __builtin_amdgcn_mfma_f32_16x16x32_bf16(xa[8 + ks].v, bfrag[0][ks], a10, 0, 0, 0);
            a11 = __builtin_amdgcn_mfma_f32_16x16x32_bf16(xa[8 + ks].v, bfrag[1][ks], a11, 0, 0, 0);
        }
        #pragma unroll
        for (int q = 0; q < 4; ++q){
            lds_g[((0 * 4 + wid) * 4 + q) * 64 + lane] = a00[q];
            lds_g[((1 * 4 + wid) * 4 + q) * 64 + lane] = a01[q];
            lds_g[((2 * 4 + wid) * 4 + q) * 64 + lane] = a10[q];
            lds_g[((3 * 4 + wid) * 4 + q) * 64 + lane] = a11[q];
        }
        __syncthreads();

        // ---- update phase: 128 threads, 2 units each ----
        unsigned pku = 0;
        if (tid < 128){
            // issue next-step xg prefetch FIRST (overlaps LDS reduce + math)
            const float* xn = xq + (size_t)(t + 1) * (BATCH * G4);
            float2 xnew[4];
            #pragma unroll
            for (int g = 0; g < 4; ++g) xnew[g] = *(const float2*)(xn + g * HID);

            float h2[2];
            #pragma unroll
            for (int du = 0; du < 2; ++du){
                int u2 = up0 + du;
                float gate[4];
                #pragma unroll
                for (int ty = 0; ty < 4; ++ty){
                    int gg = ty * 8 + u2;
                    int mtnt = mt2 * 2 + (gg >> 4);
                    int li = lb2 | (gg & 15);
                    float s = 0.0f;
                    #pragma unroll
                    for (int w = 0; w < 4; ++w)
                        s += lds_g[((mtnt * 4 + w) * 4 + reg2) * 64 + li];
                    gate[ty] = s;
                }
                float gi = gate[0] + ((du == 0) ? xv[0].x : xv[0].y);
                float gf = gate[1] + ((du == 0) ? xv[1].x : xv[1].y);
                float gc = gate[2] + ((du == 0) ? xv[2].x : xv[2].y);
                float go = gate[3] + ((du == 0) ? xv[3].x : xv[3].y);
                float c = sigf(gf) * cst[du] + sigf(gi) * tanhfast(gc);
                cst[du] = c;
                h2[du] = sigf(go) * tanhfast(c);
            }
            #pragma unroll
            for (int g = 0; g < 4; ++g) xv[g] = xnew[g];

            union { __bf16 h[2]; unsigned u; } pk;
            pk.h[0] = (__bf16)h2[0]; pk.h[1] = (__bf16)h2[1];
            pku = pk.u;
            // hot-window agent store (the ONLY store on the drain path)
            unsigned* hw = (unsigned*)(hbuf + (size_t)((t + 1) & 1) * (BATCH * HID)
                                       + (size_t)b2 * HID + jb + up0);
            __hip_atomic_store(hw, pku, __ATOMIC_RELAXED, __HIP_MEMORY_SCOPE_AGENT);
        }

        if (t + 1 == TSTEP){
            if (tid < 128)      // last step: Hall store, flushed at kernel end
                *(unsigned*)(Hall + ((size_t)t * BATCH + b2) * HID + jb + up0) = pku;
            break;
        }

        // ---- device barrier: drain hbuf store, flag, deferred Hall, poll ----
        __syncthreads();                 // vmcnt(0): hbuf agent store COMPLETE
        if (tid == 0)
            __hip_atomic_store(&flags[blockIdx.x], (unsigned)(t + 1),
                               __ATOMIC_RELAXED, __HIP_MEMORY_SCOPE_AGENT);
        if (tid < 128)                   // Hall store OFF the drain path
            *(unsigned*)(Hall + ((size_t)t * BATCH + b2) * HID + jb + up0) = pku;
        if (wid == 0){
            const unsigned tgt = (unsigned)(t + 1);
            const unsigned long long* fq = (const unsigned long long*)flags;
            for (;;){
                unsigned long long v = __hip_atomic_load(&fq[lane],
                              __ATOMIC_RELAXED, __HIP_MEMORY_SCOPE_AGENT);
                if ((unsigned)v >= tgt && (unsigned)(v >> 32) >= tgt) break;
                __builtin_amdgcn_s_sleep(1);
            }
        }
        __syncthreads();
    }
}

// ---------------------------------------------------------------------------
extern "C" void kernel_launch(void* const* d_in, const int* in_sizes, int n_in,
                              void* d_out, int out_size, void* d_ws, size_t ws_size,
                              hipStream_t stream)
{
    const float* latent = (const float*)d_in[0];
    const int*   tokens = (const int*)d_in[1];
    const float* emb    = (const float*)d_in[2];
    const float* Wlh    = (const float*)d_in[3];
    const float* blh    = (const float*)d_in[4];
    const float* Wih    = (const float*)d_in[5];
    const float* bih    = (const float*)d_in[6];
    const float* Whh    = (const float*)d_in[7];
    const float* bhh    = (const float*)d_in[8];
    const float* Wout   = (const float*)d_in[9];
    const float* bout   = (const float*)d_in[10];
    float* out = (float*)d_out;

    const size_t xg_b   = (size_t)MPAD * G4 * 4;        // 64 MiB fp32 gate preacts
    const size_t hall_b = (size_t)MPAD * HID * 2;       // 8 MiB bf16
    const size_t whh_b  = (size_t)G4 * HID * 2;         // 8 MiB bf16
    const size_t wout_b = (size_t)VOCAB * HID * 2;      // 62.5 MiB bf16
    const size_t hb_b   = (size_t)2 * BATCH * HID * 2;  // 128 KiB ping-pong
    const size_t cnt_b  = 1024;                          // 256 u32 flags

    char* p = (char*)d_ws;
    const bool wsA = ws_size >= xg_b + hall_b + whh_b + wout_b + hb_b + cnt_b;
    const bool wsB = ws_size >= hall_b + whh_b + wout_b + hb_b + cnt_b;

    float* xg;
    if (wsA){ xg = (float*)p; p += xg_b; }
    else    { xg = (float*)d_out; }      // 64 MiB scratch; consumed before K3 writes
    __bf16* Hall = (__bf16*)p; p += hall_b;
    __bf16* Whhb = (__bf16*)p; p += whh_b;
    __bf16* Woutb = nullptr;
    if (wsA || wsB){ Woutb = (__bf16*)p; p += wout_b; }
    __bf16* hbuf = (__bf16*)p; p += hb_b;
    unsigned* flags = (unsigned*)p; p += cnt_b;

    init_kernel<<<dim3(192), dim3(256), 0, stream>>>(
        latent, Wlh, blh, hbuf, Hall, flags, Whh, Whhb);

    gemm_xg<<<dim3(G4 / 128, MPAD / 128), dim3(256), 0, stream>>>(
        emb, Wih, tokens, xg, bih, bhh);

    {
        const float*  xgc   = xg;
        __bf16*       hallp = Hall;
        __bf16*       hbp   = hbuf;
        const __bf16* whhp  = Whhb;
        unsigned*     flagp = flags;
        const float*  wof   = Wout;
        __bf16*       wob   = Woutb;
        void* args[] = { (void*)&xgc, (void*)&hallp, (void*)&hbp, (void*)&whhp,
                         (void*)&flagp, (void*)&wof, (void*)&wob };
        hipLaunchCooperativeKernel((void*)lstm_coop, dim3(2 * NBLK), dim3(256),
                                   args, 0, stream);
    }

    if (Woutb)
        gemm_logits<1><<<dim3(NTM * NTN), dim3(256), 0, stream>>>(
            Hall, (const float*)nullptr, Woutb, out, bout);
    else
        gemm_logits<0><<<dim3(NTM * NTN), dim3(256), 0, stream>>>(
            Hall, Wout, (const __bf16*)nullptr, out, bout);
}

// Round 12
// 1213.755 us; speedup vs baseline: 1.3008x; 1.1644x over previous
//
#include <hip/hip_runtime.h>
#include <cstdint>

typedef __bf16 bf16x8 __attribute__((ext_vector_type(8)));
typedef __bf16 bf16x4 __attribute__((ext_vector_type(4)));
typedef float  f32x4  __attribute__((ext_vector_type(4)));

#define VOCAB 32000
#define EMB   512
#define HID   1024
#define LAT   512
#define BATCH 32
#define TSTEP 127          // T-1
#define MROWS 4064         // TSTEP*BATCH
#define MPAD  4096
#define G4    4096         // 4*HID
#define NBLK  128          // lstm worker blocks
#define NTM   32           // logits M tiles
#define NTN   250          // logits N tiles
#define FSTRIDE 64         // flag spacing in u32 (256 B apart, line-exclusive)

__device__ __forceinline__ float sigf(float x){ return 1.0f / (1.0f + __expf(-x)); }
__device__ __forceinline__ float tanhfast(float x){
    float ax = fabsf(x);
    float e  = __expf(-2.0f * ax);
    float t  = (1.0f - e) / (1.0f + e);
    return copysignf(t, x);
}

// async global->LDS, 16B/lane; LDS base wave-uniform (HW adds lane*16)
__device__ __forceinline__ void gll16(void* lds, const void* gsrc){
    __builtin_amdgcn_global_load_lds(
        (const __attribute__((address_space(1))) unsigned int*)gsrc,
        (__attribute__((address_space(3))) unsigned int*)lds,
        16, 0, 0);
}

// ---------------------------------------------------------------------------
// K0 (grid 192): blocks 0..127: h0 = latent@W_lh^T + b_lh -> hbuf[0]; zero
// Hall pad rows; zero scattered flags. blocks 128..191: W_hh fp32->bf16.
// ---------------------------------------------------------------------------
__global__ __launch_bounds__(256) void init_kernel(
    const float* __restrict__ latent,
    const float* __restrict__ Wlh,
    const float* __restrict__ blh,
    __bf16* __restrict__ h0,
    __bf16* __restrict__ Hall,
    unsigned* __restrict__ flags,
    const float* __restrict__ Whh,
    __bf16* __restrict__ Whhb)
{
    if (blockIdx.x >= 128){
        const int n4 = G4 * HID / 4;
        for (int i = (blockIdx.x - 128) * 256 + threadIdx.x; i < n4; i += 64 * 256){
            float4 v = ((const float4*)Whh)[i];
            bf16x4 o = { (__bf16)v.x, (__bf16)v.y, (__bf16)v.z, (__bf16)v.w };
            ((bf16x4*)Whhb)[i] = o;
        }
        return;
    }
    if (blockIdx.x == 0 && threadIdx.x < NBLK)
        flags[threadIdx.x * FSTRIDE] = 0u;     // one flag per 256B line

    int id = blockIdx.x * 256 + threadIdx.x;   // 32768 = BATCH*HID
    int b = id >> 10, j = id & 1023;
    float s = blh[j];
    const float4* lr = (const float4*)(latent + (size_t)b * LAT);
    const float4* wr = (const float4*)(Wlh + (size_t)j * LAT);
    for (int k = 0; k < LAT / 4; ++k){
        float4 a = lr[k], w = wr[k];
        s += a.x * w.x + a.y * w.y + a.z * w.z + a.w * w.w;
    }
    h0[id] = (__bf16)s;                         // hbuf[0][b][j]
    Hall[(size_t)MROWS * HID + id] = (__bf16)0.0f;  // pad rows 4064..4095
}

// ---------------------------------------------------------------------------
// K1: xg[r][4096] = emb[tok(r)] @ W_ih^T + b_ih + b_hh   (fp32 in, fp32 out)
// ---------------------------------------------------------------------------
__global__ __launch_bounds__(256) void gemm_xg(
    const float* __restrict__ emb,
    const float* __restrict__ Wih,
    const int*   __restrict__ tok,
    float*       __restrict__ xg,
    const float* __restrict__ bih,
    const float* __restrict__ bhh)
{
    __shared__ __bf16 As[2][128 * 32];
    __shared__ __bf16 Bs[2][128 * 32];

    const int tid  = threadIdx.x;
    const int wid  = tid >> 6, lane = tid & 63;
    const int tile_n = blockIdx.x, tile_m = blockIdx.y;
    const int wr = wid >> 1, wc = wid & 1;

    f32x4 acc[4][4] = {};

    auto stage = [&](int kt, int buf){
        #pragma unroll
        for (int j = 0; j < 2; ++j){
            const int slot = tid + j * 256;
            const int row  = slot >> 2;
            const int kb   = kt * 32 + (slot & 3) * 8;
            {
                const int brow = tile_n * 128 + row;
                const float4* p = (const float4*)(Wih + (size_t)brow * EMB + kb);
                float4 u = p[0], v = p[1];
                bf16x8 w = { (__bf16)u.x, (__bf16)u.y, (__bf16)u.z, (__bf16)u.w,
                             (__bf16)v.x, (__bf16)v.y, (__bf16)v.z, (__bf16)v.w };
                *(bf16x8*)&Bs[buf][row * 32 + (slot & 3) * 8] = w;
            }
            {
                int r = tile_m * 128 + row;
                int rc = (r < MROWS) ? r : (MROWS - 1);
                int token = tok[(rc & 31) * 128 + (rc >> 5)];   // tokens[b][t]
                const float4* p = (const float4*)(emb + (size_t)token * EMB + kb);
                float4 u = p[0], v = p[1];
                bf16x8 w = { (__bf16)u.x, (__bf16)u.y, (__bf16)u.z, (__bf16)u.w,
                             (__bf16)v.x, (__bf16)v.y, (__bf16)v.z, (__bf16)v.w };
                *(bf16x8*)&As[buf][row * 32 + (slot & 3) * 8] = w;
            }
        }
    };

    const int KT = EMB / 32;
    stage(0, 0);
    for (int kt = 0; kt < KT; ++kt){
        const int buf = kt & 1;
        __syncthreads();
        if (kt + 1 < KT) stage(kt + 1, buf ^ 1);
        const __bf16* Abuf = As[buf];
        const __bf16* Bbuf = Bs[buf];
        const int ar = lane & 15, ko = (lane >> 4) * 8;
        bf16x8 av[4], bv[4];
        #pragma unroll
        for (int m = 0; m < 4; ++m)
            av[m] = *(const bf16x8*)&Abuf[(wr * 64 + m * 16 + ar) * 32 + ko];
        #pragma unroll
        for (int n = 0; n < 4; ++n)
            bv[n] = *(const bf16x8*)&Bbuf[(wc * 64 + n * 16 + ar) * 32 + ko];
        #pragma unroll
        for (int m = 0; m < 4; ++m)
            #pragma unroll
            for (int n = 0; n < 4; ++n)
                acc[m][n] = __builtin_amdgcn_mfma_f32_16x16x32_bf16(av[m], bv[n], acc[m][n], 0, 0, 0);
    }

    const int r0 = tile_m * 128 + wr * 64 + ((lane >> 4) << 2);
    const int c0 = tile_n * 128 + wc * 64 + (lane & 15);
    #pragma unroll
    for (int m = 0; m < 4; ++m){
        #pragma unroll
        for (int n = 0; n < 4; ++n){
            const int col = c0 + n * 16;
            float badd = bih[col] + bhh[col];
            #pragma unroll
            for (int q = 0; q < 4; ++q){
                int row = r0 + m * 16 + q;
                xg[(size_t)row * G4 + col] = acc[m][n][q] + badd;
            }
        }
    }
}

// ---------------------------------------------------------------------------
// K3: logits = Hall @ W_out^T + b_out  (fp32 out, scattered to out[b][t][v])
// GROUP_M=8 super-tiles + bijective XCD swizzle (nwg=8000 % 8 == 0).
// ---------------------------------------------------------------------------
template<int BF16B>
__global__ __launch_bounds__(256) void gemm_logits(
    const __bf16* __restrict__ A,     // Hall, padded to MPAD rows, K=HID
    const float*  __restrict__ Bf,    // W_out fp32 (BF16B=0)
    const __bf16* __restrict__ Bb,    // W_out bf16 (BF16B=1)
    float*        __restrict__ C,
    const float*  __restrict__ bias)
{
    __shared__ __bf16 As[2][128 * 32];
    __shared__ __bf16 Bs[2][128 * 32];

    const int tid  = threadIdx.x;
    const int wid  = tid >> 6, lane = tid & 63;
    const int bid = blockIdx.x;
    const int s   = (bid & 7) * (NTM * NTN / 8) + (bid >> 3);
    const int g   = s / (8 * NTN), rem = s % (8 * NTN);
    const int tile_m = g * 8 + (rem & 7);
    const int tile_n = rem >> 3;
    const int wr = wid >> 1, wc = wid & 1;

    f32x4 acc[4][4] = {};

    auto stage = [&](int kt, int buf){
        const int kb = kt * 32 + (lane & 3) * 8;
        #pragma unroll
        for (int c2 = 0; c2 < 2; ++c2){
            int rA = tile_m * 128 + c2 * 64 + wid * 16 + (lane >> 2);
            gll16(&As[buf][c2 * 2048 + wid * 512], A + (size_t)rA * HID + kb);
            if constexpr (BF16B){
                int rB = tile_n * 128 + c2 * 64 + wid * 16 + (lane >> 2);
                gll16(&Bs[buf][c2 * 2048 + wid * 512], Bb + (size_t)rB * HID + kb);
            }
        }
        if constexpr (!BF16B){
            #pragma unroll
            for (int j = 0; j < 2; ++j){
                const int slot = tid + j * 256;
                const int row  = slot >> 2;
                const int kb2  = kt * 32 + (slot & 3) * 8;
                const int brow = tile_n * 128 + row;
                const float4* p = (const float4*)(Bf + (size_t)brow * HID + kb2);
                float4 u = p[0], v = p[1];
                bf16x8 w = { (__bf16)u.x, (__bf16)u.y, (__bf16)u.z, (__bf16)u.w,
                             (__bf16)v.x, (__bf16)v.y, (__bf16)v.z, (__bf16)v.w };
                *(bf16x8*)&Bs[buf][row * 32 + (slot & 3) * 8] = w;
            }
        }
    };

    const int KT = HID / 32;
    stage(0, 0);
    for (int kt = 0; kt < KT; ++kt){
        const int buf = kt & 1;
        __syncthreads();                 // drains vmcnt (gll) + lgkmcnt
        if (kt + 1 < KT) stage(kt + 1, buf ^ 1);
        const __bf16* Abuf = As[buf];
        const __bf16* Bbuf = Bs[buf];
        const int ar = lane & 15, ko = (lane >> 4) * 8;
        bf16x8 av[4], bv[4];
        #pragma unroll
        for (int m = 0; m < 4; ++m)
            av[m] = *(const bf16x8*)&Abuf[(wr * 64 + m * 16 + ar) * 32 + ko];
        #pragma unroll
        for (int n = 0; n < 4; ++n)
            bv[n] = *(const bf16x8*)&Bbuf[(wc * 64 + n * 16 + ar) * 32 + ko];
        #pragma unroll
        for (int m = 0; m < 4; ++m)
            #pragma unroll
            for (int n = 0; n < 4; ++n)
                acc[m][n] = __builtin_amdgcn_mfma_f32_16x16x32_bf16(av[m], bv[n], acc[m][n], 0, 0, 0);
    }

    const int r0 = tile_m * 128 + wr * 64 + ((lane >> 4) << 2);
    const int c0 = tile_n * 128 + wc * 64 + (lane & 15);
    #pragma unroll
    for (int m = 0; m < 4; ++m){
        #pragma unroll
        for (int n = 0; n < 4; ++n){
            const int col = c0 + n * 16;
            float badd = bias[col];
            #pragma unroll
            for (int q = 0; q < 4; ++q){
                int row = r0 + m * 16 + q;
                if (row < MROWS){
                    int t = row >> 5, b = row & 31;
                    __builtin_nontemporal_store(acc[m][n][q] + badd,
                        &C[((size_t)b * TSTEP + t) * VOCAB + col]);
                }
            }
        }
    }
}

// ---------------------------------------------------------------------------
// K2: 127 LSTM steps, ONE cooperative kernel (256 blocks):
//   blocks 0..127   : LSTM. h exchange via SMALL hbuf ping-pong (agent
//                     atomics, hot at coherence point). Hall plain-store
//                     DEFERRED past the drain (fire-and-forget during poll).
//   blocks 128..255 : W_out fp32->bf16 under the lstm shadow, then exit.
// Barrier: SCATTERED per-block flag (one per 256B line -> conflict-free
// arrival stores) + wave0 parallel poll (2 flags/lane).
// ---------------------------------------------------------------------------
__global__ __launch_bounds__(256) void lstm_coop(
    const float*  __restrict__ xg,
    __bf16*       __restrict__ Hall,
    __bf16*       __restrict__ hbuf,    // 2 * BATCH*HID ping-pong, [0]=h0
    const __bf16* __restrict__ Whhb,
    unsigned*     __restrict__ flags,   // 128 flags, 256B apart
    const float*  __restrict__ Woutf,
    __bf16*       __restrict__ Woutb)
{
    if (blockIdx.x >= NBLK){
        if (Woutb){
            const int n4 = VOCAB * HID / 4;          // 8.192M float4
            for (int i = (blockIdx.x - NBLK) * 256 + threadIdx.x; i < n4; i += NBLK * 256){
                float4 v = ((const float4*)Woutf)[i];
                bf16x4 o = { (__bf16)v.x, (__bf16)v.y, (__bf16)v.z, (__bf16)v.w };
                ((bf16x4*)Woutb)[i] = o;
            }
        }
        return;
    }

    __shared__ float lds_g[4 * 4 * 4 * 64];    // [acc][wid][reg][lane] = 16KB
    const int tid = threadIdx.x, wid = tid >> 6, lane = tid & 63;
    const int jb = blockIdx.x * 8;

    // W_hh fragments for our 32 gate cols, this wave's K-quarter (64 VGPRs)
    bf16x8 bfrag[2][8];
    {
        const int gl = lane & 15, ko = (lane >> 4) * 8;
        #pragma unroll
        for (int nt = 0; nt < 2; ++nt){
            int gg = nt * 16 + gl;                     // type=gg>>3, unit=gg&7
            const __bf16* base =
                Whhb + (size_t)((gg >> 3) * HID + jb + (gg & 7)) * HID + wid * 256 + ko;
            #pragma unroll
            for (int ks = 0; ks < 8; ++ks)
                bfrag[nt][ks] = *(const bf16x8*)(base + ks * 32);
        }
    }

    // update-phase ownership: tid<128, 2 units each -> 4B-packed h stores
    const int b2 = tid >> 2, up0 = (tid & 3) * 2;
    const int mt2 = b2 >> 4, r2 = b2 & 15, reg2 = r2 & 3, lb2 = (r2 >> 2) << 4;
    float cst[2] = {0.0f, 0.0f};

    const float* xq = xg + (size_t)b2 * G4 + jb + up0;
    float2 xv[4];
    if (tid < 128){
        #pragma unroll
        for (int g = 0; g < 4; ++g) xv[g] = *(const float2*)(xq + g * HID);
    }

    const size_t e0 = (size_t)(lane & 15) * HID + wid * 256 + (lane >> 4) * 8; // elems

    for (int t = 0; t < TSTEP; ++t){
        // ---- batched h loads from hot hbuf window (agent atomics) ----
        const unsigned long long* hq =
            (const unsigned long long*)(hbuf + (size_t)(t & 1) * (BATCH * HID));
        union { unsigned long long q[2]; bf16x8 v; } xa[16];
        #pragma unroll
        for (int ks = 0; ks < 8; ++ks){
            size_t q0 = (e0 + (size_t)ks * 32) >> 2;
            size_t q1 = q0 + ((size_t)16 * HID >> 2);
            xa[ks].q[0]     = __hip_atomic_load(hq + q0,     __ATOMIC_RELAXED, __HIP_MEMORY_SCOPE_AGENT);
            xa[ks].q[1]     = __hip_atomic_load(hq + q0 + 1, __ATOMIC_RELAXED, __HIP_MEMORY_SCOPE_AGENT);
            xa[8 + ks].q[0] = __hip_atomic_load(hq + q1,     __ATOMIC_RELAXED, __HIP_MEMORY_SCOPE_AGENT);
            xa[8 + ks].q[1] = __hip_atomic_load(hq + q1 + 1, __ATOMIC_RELAXED, __HIP_MEMORY_SCOPE_AGENT);
        }
        f32x4 a00 = {}, a01 = {}, a10 = {}, a11 = {};
        #pragma unroll
        for (int ks = 0; ks < 8; ++ks){
            a00 = __builtin_amdgcn_mfma_f32_16x16x32_bf16(xa[ks].v,     bfrag[0][ks], a00, 0, 0, 0);
            a01 = __builtin_amdgcn_mfma_f32_16x16x32_bf16(xa[ks].v,     bfrag[1][ks], a01, 0, 0, 0);
            a10 = __builtin_amdgcn_mfma_f32_16x16x32_bf16(xa[8 + ks].v, bfrag[0][ks], a10, 0, 0, 0);
            a11 = __builtin_amdgcn_mfma_f32_16x16x32_bf16(xa[8 + ks].v, bfrag[1][ks], a11, 0, 0, 0);
        }
        #pragma unroll
        for (int q = 0; q < 4; ++q){
            lds_g[((0 * 4 + wid) * 4 + q) * 64 + lane] = a00[q];
            lds_g[((1 * 4 + wid) * 4 + q) * 64 + lane] = a01[q];
            lds_g[((2 * 4 + wid) * 4 + q) * 64 + lane] = a10[q];
            lds_g[((3 * 4 + wid) * 4 + q) * 64 + lane] = a11[q];
        }
        __syncthreads();

        // ---- update phase: 128 threads, 2 units each ----
        unsigned pku = 0;
        if (tid < 128){
            // issue next-step xg prefetch FIRST (overlaps LDS reduce + math)
            const float* xn = xq + (size_t)(t + 1) * (BATCH * G4);
            float2 xnew[4];
            #pragma unroll
            for (int g = 0; g < 4; ++g) xnew[g] = *(const float2*)(xn + g * HID);

            float h2[2];
            #pragma unroll
            for (int du = 0; du < 2; ++du){
                int u2 = up0 + du;
                float gate[4];
                #pragma unroll
                for (int ty = 0; ty < 4; ++ty){
                    int gg = ty * 8 + u2;
                    int mtnt = mt2 * 2 + (gg >> 4);
                    int li = lb2 | (gg & 15);
                    float s = 0.0f;
                    #pragma unroll
                    for (int w = 0; w < 4; ++w)
                        s += lds_g[((mtnt * 4 + w) * 4 + reg2) * 64 + li];
                    gate[ty] = s;
                }
                float gi = gate[0] + ((du == 0) ? xv[0].x : xv[0].y);
                float gf = gate[1] + ((du == 0) ? xv[1].x : xv[1].y);
                float gc = gate[2] + ((du == 0) ? xv[2].x : xv[2].y);
                float go = gate[3] + ((du == 0) ? xv[3].x : xv[3].y);
                float c = sigf(gf) * cst[du] + sigf(gi) * tanhfast(gc);
                cst[du] = c;
                h2[du] = sigf(go) * tanhfast(c);
            }
            #pragma unroll
            for (int g = 0; g < 4; ++g) xv[g] = xnew[g];

            union { __bf16 h[2]; unsigned u; } pk;
            pk.h[0] = (__bf16)h2[0]; pk.h[1] = (__bf16)h2[1];
            pku = pk.u;
            // hot-window agent store (the ONLY store on the drain path)
            unsigned* hw = (unsigned*)(hbuf + (size_t)((t + 1) & 1) * (BATCH * HID)
                                       + (size_t)b2 * HID + jb + up0);
            __hip_atomic_store(hw, pku, __ATOMIC_RELAXED, __HIP_MEMORY_SCOPE_AGENT);
        }

        if (t + 1 == TSTEP){
            if (tid < 128)      // last step: Hall store, flushed at kernel end
                *(unsigned*)(Hall + ((size_t)t * BATCH + b2) * HID + jb + up0) = pku;
            break;
        }

        // ---- device barrier: drain hbuf store, flag, deferred Hall, poll ----
        __syncthreads();                 // vmcnt(0): hbuf agent store COMPLETE
        if (tid == 0)
            __hip_atomic_store(&flags[blockIdx.x * FSTRIDE], (unsigned)(t + 1),
                               __ATOMIC_RELAXED, __HIP_MEMORY_SCOPE_AGENT);
        if (tid < 128)                   // Hall store OFF the drain path
            *(unsigned*)(Hall + ((size_t)t * BATCH + b2) * HID + jb + up0) = pku;
        if (wid == 0){
            const unsigned tgt = (unsigned)(t + 1);
            for (;;){
                unsigned f0 = __hip_atomic_load(&flags[lane * FSTRIDE],
                                  __ATOMIC_RELAXED, __HIP_MEMORY_SCOPE_AGENT);
                unsigned f1 = __hip_atomic_load(&flags[(lane + 64) * FSTRIDE],
                                  __ATOMIC_RELAXED, __HIP_MEMORY_SCOPE_AGENT);
                if (f0 >= tgt && f1 >= tgt) break;
                __builtin_amdgcn_s_sleep(1);
            }
        }
        __syncthreads();
    }
}

// ---------------------------------------------------------------------------
extern "C" void kernel_launch(void* const* d_in, const int* in_sizes, int n_in,
                              void* d_out, int out_size, void* d_ws, size_t ws_size,
                              hipStream_t stream)
{
    const float* latent = (const float*)d_in[0];
    const int*   tokens = (const int*)d_in[1];
    const float* emb    = (const float*)d_in[2];
    const float* Wlh    = (const float*)d_in[3];
    const float* blh    = (const float*)d_in[4];
    const float* Wih    = (const float*)d_in[5];
    const float* bih    = (const float*)d_in[6];
    const float* Whh    = (const float*)d_in[7];
    const float* bhh    = (const float*)d_in[8];
    const float* Wout   = (const float*)d_in[9];
    const float* bout   = (const float*)d_in[10];
    float* out = (float*)d_out;

    const size_t xg_b   = (size_t)MPAD * G4 * 4;        // 64 MiB fp32 gate preacts
    const size_t hall_b = (size_t)MPAD * HID * 2;       // 8 MiB bf16
    const size_t whh_b  = (size_t)G4 * HID * 2;         // 8 MiB bf16
    const size_t wout_b = (size_t)VOCAB * HID * 2;      // 62.5 MiB bf16
    const size_t hb_b   = (size_t)2 * BATCH * HID * 2;  // 128 KiB ping-pong
    const size_t cnt_b  = (size_t)NBLK * FSTRIDE * 4;   // 32 KiB scattered flags

    char* p = (char*)d_ws;
    const bool wsA = ws_size >= xg_b + hall_b + whh_b + wout_b + hb_b + cnt_b;
    const bool wsB = ws_size >= hall_b + whh_b + wout_b + hb_b + cnt_b;

    float* xg;
    if (wsA){ xg = (float*)p; p += xg_b; }
    else    { xg = (float*)d_out; }      // 64 MiB scratch; consumed before K3 writes
    __bf16* Hall = (__bf16*)p; p += hall_b;
    __bf16* Whhb = (__bf16*)p; p += whh_b;
    __bf16* Woutb = nullptr;
    if (wsA || wsB){ Woutb = (__bf16*)p; p += wout_b; }
    __bf16* hbuf = (__bf16*)p; p += hb_b;
    unsigned* flags = (unsigned*)p; p += cnt_b;

    init_kernel<<<dim3(192), dim3(256), 0, stream>>>(
        latent, Wlh, blh, hbuf, Hall, flags, Whh, Whhb);

    gemm_xg<<<dim3(G4 / 128, MPAD / 128), dim3(256), 0, stream>>>(
        emb, Wih, tokens, xg, bih, bhh);

    {
        const float*  xgc   = xg;
        __bf16*       hallp = Hall;
        __bf16*       hbp   = hbuf;
        const __bf16* whhp  = Whhb;
        unsigned*     flagp = flags;
        const float*  wof   = Wout;
        __bf16*       wob   = Woutb;
        void* args[] = { (void*)&xgc, (void*)&hallp, (void*)&hbp, (void*)&whhp,
                         (void*)&flagp, (void*)&wof, (void*)&wob };
        hipLaunchCooperativeKernel((void*)lstm_coop, dim3(2 * NBLK), dim3(256),
                                   args, 0, stream);
    }

    if (Woutb)
        gemm_logits<1><<<dim3(NTM * NTN), dim3(256), 0, stream>>>(
            Hall, (const float*)nullptr, Woutb, out, bout);
    else
        gemm_logits<0><<<dim3(NTM * NTN), dim3(256), 0, stream>>>(
            Hall, Wout, (const __bf16*)nullptr, out, bout);
}